// Round 2
// baseline (2211.160 us; speedup 1.0000x reference)
//
#include <hip/hip_runtime.h>

// ---------------------------------------------------------------------------
// InvariantPointAttention, N=1024 C1=384 C2=128 H=12 SQK=SV=16 PQK=4 PV=8
// All inputs/outputs FLOAT32 (reference dtypes). Internal f32.
// k1: prep point_weights (softplus) -> f32 ws
// k2: QKV projections (scalar + point w/ rigid transform) -> f32 ws
// k3: fused attention w/ online softmax over k-chunks (KC=128), TQ=4 q/block
// k4: final (1024x2112)@(2112x384) GEMM -> f32 out
// ---------------------------------------------------------------------------

#define NQ 1024
#define C1D 384
#define C2D 128
#define HH 12
#define FEATD 2112
#define NCHD 384

// ------------------------------- k1: prep ----------------------------------
__global__ void k_prep(const float* __restrict__ raw, float* __restrict__ pwf) {
  int t = threadIdx.x;
  if (t < HH) {
    float x = raw[t];
    pwf[t] = 0.23570226039551584f * log1pf(expf(x)); // sqrt(1/(PQK*9/2))*softplus
  }
}

// ---------------------------- k2: projections ------------------------------
// grid (128, 3), block 256. Each block: 8 rows of inputs_1d, 256 "units".
// units: [0,192) qs | [192,384) ks | [384,576) vs | [576,624) qp |
//        [624,672) kp | [672,768) vp
__global__ __launch_bounds__(256) void k_proj(
    const float* __restrict__ x1d, const float* __restrict__ rot, const float* __restrict__ trans,
    const float* __restrict__ wq_p, const float* __restrict__ bq_p,
    const float* __restrict__ wk_p, const float* __restrict__ bk_p,
    const float* __restrict__ wv_p, const float* __restrict__ bv_p,
    const float* __restrict__ wq_s, const float* __restrict__ wk_s, const float* __restrict__ wv_s,
    float* __restrict__ qs, float* __restrict__ ks_, float* __restrict__ vs,
    float* __restrict__ qp, float* __restrict__ kp, float* __restrict__ vp) {
  __shared__ float xs[8 * C1D];
  const int n0 = blockIdx.x * 8;
  const int t = threadIdx.x;
  for (int i = t; i < 8 * C1D; i += 256) xs[i] = x1d[(size_t)n0 * C1D + i];
  __syncthreads();
  const int u = blockIdx.y * 256 + t;
  if (u < 576) {
    const float* W; float* dst; float scale = 1.0f; int col;
    if (u < 192)      { W = wq_s; dst = qs;  col = u;       scale = 0.25f; }
    else if (u < 384) { W = wk_s; dst = ks_; col = u - 192; }
    else              { W = wv_s; dst = vs;  col = u - 384; }
    float acc[8];
#pragma unroll
    for (int r = 0; r < 8; ++r) acc[r] = 0.f;
    for (int c = 0; c < C1D; ++c) {
      float w = W[c * 192 + col];
#pragma unroll
      for (int r = 0; r < 8; ++r) acc[r] += xs[r * C1D + c] * w;
    }
    for (int r = 0; r < 8; ++r) dst[(size_t)(n0 + r) * 192 + col] = acc[r] * scale;
  } else {
    const float* W; const float* B; float* dst; int h, p, np_;
    if (u < 624)      { W = wq_p; B = bq_p; dst = qp; int v = u - 576; h = v / 4; p = v % 4; np_ = 4; }
    else if (u < 672) { W = wk_p; B = bk_p; dst = kp; int v = u - 624; h = v / 4; p = v % 4; np_ = 4; }
    else              { W = wv_p; B = bv_p; dst = vp; int v = u - 672; h = v / 8; p = v % 8; np_ = 8; }
    const int str = 36 * np_;          // H*3*np_ (row stride of W, also per-n out stride)
    const int c0 = h * 3 * np_ + p;    // local dims at c0 + j*np_
    float a0[8], a1[8], a2[8];
#pragma unroll
    for (int r = 0; r < 8; ++r) { a0[r] = 0.f; a1[r] = 0.f; a2[r] = 0.f; }
    for (int c = 0; c < C1D; ++c) {
      float w0 = W[c * str + c0];
      float w1 = W[c * str + c0 + np_];
      float w2 = W[c * str + c0 + 2 * np_];
#pragma unroll
      for (int r = 0; r < 8; ++r) {
        float x = xs[r * C1D + c];
        a0[r] += x * w0; a1[r] += x * w1; a2[r] += x * w2;
      }
    }
    const float b0 = B[c0], b1 = B[c0 + np_], b2 = B[c0 + 2 * np_];
    for (int r = 0; r < 8; ++r) {
      const int n = n0 + r;
      float l0 = a0[r] + b0, l1 = a1[r] + b1, l2 = a2[r] + b2;
      float R0 = rot[n * 9 + 0], R1 = rot[n * 9 + 1], R2 = rot[n * 9 + 2];
      float R3 = rot[n * 9 + 3], R4 = rot[n * 9 + 4], R5 = rot[n * 9 + 5];
      float R6 = rot[n * 9 + 6], R7 = rot[n * 9 + 7], R8 = rot[n * 9 + 8];
      float T0 = trans[n * 3 + 0], T1 = trans[n * 3 + 1], T2 = trans[n * 3 + 2];
      float g0 = R0 * l0 + R1 * l1 + R2 * l2 + T0;
      float g1 = R3 * l0 + R4 * l1 + R5 * l2 + T1;
      float g2 = R6 * l0 + R7 * l1 + R8 * l2 + T2;
      size_t o = (size_t)n * str + (size_t)(h * np_ + p) * 3;
      dst[o] = g0; dst[o + 1] = g1; dst[o + 2] = g2;
    }
  }
}

// --------------------------- k3: fused attention ---------------------------
// grid 256, block 512. TQ=4 q-rows/block (tq = t>>7, l = t&127). KC=128.
__global__ __launch_bounds__(512) void k_attn(
    const float* __restrict__ x2d, const float* __restrict__ mask,
    const float* __restrict__ rot, const float* __restrict__ trans,
    const float* __restrict__ w2d, const float* __restrict__ b2d, const float* __restrict__ pwf,
    const float* __restrict__ qs, const float* __restrict__ ks_, const float* __restrict__ vs,
    const float* __restrict__ qp, const float* __restrict__ kp, const float* __restrict__ vp,
    float* __restrict__ feat) {
  __shared__ __attribute__((aligned(16))) float Lp[4 * 128 * 12]; // logits/probs
  __shared__ float m_l[48], s_l[48], a_l[48];
  __shared__ float G_l[4 * 96 * 3];

  const int t = threadIdx.x;
  const int tq = t >> 7;
  const int l = t & 127;
  const int q0 = blockIdx.x * 4;
  const int q = q0 + tq;

  if (t < 48) { m_l[t] = -3.0e38f; s_l[t] = 0.f; }

  float bh[12], pw[12];
#pragma unroll
  for (int h = 0; h < 12; ++h) { bh[h] = b2d[h]; pw[h] = pwf[h]; }
  const float mq = mask[q];

  // small-accumulator (v_scalar 16 + v_point 24 = 40 per head) element map
  int hj[4] = {0, 0, 0, 0}, offj[4] = {0, 0, 0, 0}, strj[4] = {192, 192, 192, 192};
  const float* basej[4] = {vs, vs, vs, vs};
  const bool dact = (l < 120);
  if (dact) {
#pragma unroll
    for (int j = 0; j < 4; ++j) {
      int e = l * 4 + j, h = e / 40, r = e % 40;
      hj[j] = h;
      if (r < 16) { basej[j] = vs; strj[j] = 192; offj[j] = h * 16 + r; }
      else        { basej[j] = vp; strj[j] = 288; offj[j] = h * 24 + (r - 16); }
    }
  }

  float r2d[12];
#pragma unroll
  for (int h = 0; h < 12; ++h) r2d[h] = 0.f;
  float vald[4] = {0.f, 0.f, 0.f, 0.f};

  const float* qr = qs + (size_t)q * 192;   // wave-uniform
  const float* qpr = qp + (size_t)q * 144;  // wave-uniform
  __syncthreads();

  for (int kc = 0; kc < 8; ++kc) {
    const int k0 = kc * 128;
    const int k = k0 + l;
    // ---- phase A: logits for (tq, k) across all 12 heads ----
    {
      float acc[12];
#pragma unroll
      for (int h = 0; h < 12; ++h) acc[h] = bh[h];
      const float4* xr4 = (const float4*)(x2d + ((size_t)q * NQ + (size_t)k) * C2D);
      for (int g = 0; g < 32; ++g) {
        float4 xv = xr4[g];
        const float* wr = w2d + (g * 4) * 12;   // wave-uniform address
#pragma unroll
        for (int h = 0; h < 12; ++h)
          acc[h] += xv.x * wr[h] + xv.y * wr[12 + h] + xv.z * wr[24 + h] + xv.w * wr[36 + h];
      }
      const float4* kr4 = (const float4*)(ks_ + (size_t)k * 192);
      const float4* qr4 = (const float4*)qr;
#pragma unroll
      for (int h = 0; h < 12; ++h) {
        float d = 0.f;
#pragma unroll
        for (int j = 0; j < 4; ++j) {
          float4 a = qr4[h * 4 + j]; float4 b = kr4[h * 4 + j];
          d += a.x * b.x + a.y * b.y + a.z * b.z + a.w * b.w;
        }
        acc[h] += d;
      }
      const float* kpr = kp + (size_t)k * 144;
#pragma unroll
      for (int h = 0; h < 12; ++h) {
        float d2 = 0.f;
#pragma unroll
        for (int p = 0; p < 4; ++p) {
          int b = (h * 4 + p) * 3;
          float dx = qpr[b] - kpr[b];
          float dy = qpr[b + 1] - kpr[b + 1];
          float dz = qpr[b + 2] - kpr[b + 2];
          d2 += dx * dx + dy * dy + dz * dz;
        }
        acc[h] -= 0.5f * pw[h] * d2;
      }
      const float mk = mask[k];
      const float mt = -100000.0f * (1.0f - mq * mk);
      float* Lr = &Lp[(tq * 128 + l) * 12];
#pragma unroll
      for (int h = 0; h < 12; ++h) Lr[h] = (acc[h] + mt) * 0.5773502691896258f;
    }
    __syncthreads();
    // ---- B1: chunk max, alpha ----
    if (t < 48) {
      const int t1 = t / 12, h1 = t % 12;
      const float* base = &Lp[t1 * 1536 + h1];
      float mc = -3.0e38f;
      for (int kk = 0; kk < 128; ++kk) mc = fmaxf(mc, base[kk * 12]);
      float mo = m_l[t], mn = fmaxf(mo, mc);
      a_l[t] = expf(mo - mn);
      m_l[t] = mn;
    }
    __syncthreads();
    // ---- B2: exp in place + rescale accumulators ----
    {
      float* Lr = &Lp[(tq * 128 + l) * 12];
#pragma unroll
      for (int h = 0; h < 12; ++h) Lr[h] = expf(Lr[h] - m_l[tq * 12 + h]);
#pragma unroll
      for (int h = 0; h < 12; ++h) r2d[h] *= a_l[tq * 12 + h];
      if (dact) {
#pragma unroll
        for (int j = 0; j < 4; ++j) vald[j] *= a_l[tq * 12 + hj[j]];
      }
    }
    __syncthreads();
    // ---- B3: denominator update (t<48 only; runs alongside C/D) ----
    if (t < 48) {
      const int t1 = t / 12, h1 = t % 12;
      const float* base = &Lp[t1 * 1536 + h1];
      float sum = 0.f;
      for (int kk = 0; kk < 128; ++kk) sum += base[kk * 12];
      s_l[t] = s_l[t] * a_l[t] + sum;
    }
    // ---- C: res_2d accumulate (thread owns channel c=l for its tq) ----
    {
      const float* xc = x2d + ((size_t)q * NQ + (size_t)k0) * C2D + l;
      const float4* Pr = (const float4*)&Lp[tq * 1536];
      for (int kk = 0; kk < 128; ++kk) {
        float xv = xc[(size_t)kk * C2D];
        float4 p0 = Pr[kk * 3], p1 = Pr[kk * 3 + 1], p2 = Pr[kk * 3 + 2];
        r2d[0] += p0.x * xv; r2d[1] += p0.y * xv; r2d[2]  += p0.z * xv; r2d[3]  += p0.w * xv;
        r2d[4] += p1.x * xv; r2d[5] += p1.y * xv; r2d[6]  += p1.z * xv; r2d[7]  += p1.w * xv;
        r2d[8] += p2.x * xv; r2d[9] += p2.y * xv; r2d[10] += p2.z * xv; r2d[11] += p2.w * xv;
      }
    }
    // ---- D: v_scalar / v_point accumulate ----
    if (dact) {
      for (int kk = 0; kk < 128; ++kk) {
        const float* pb = &Lp[(tq * 128 + kk) * 12];
        const int k2 = k0 + kk;
#pragma unroll
        for (int j = 0; j < 4; ++j)
          vald[j] += pb[hj[j]] * basej[j][(size_t)k2 * strj[j] + offj[j]];
      }
    }
    __syncthreads();
  }
  // ---- epilogue ----
  if (t < 48) a_l[t] = 1.0f / s_l[t];
  __syncthreads();
  {
    float* fr = feat + (size_t)q * FEATD + 576 + l;
#pragma unroll
    for (int h = 0; h < 12; ++h) fr[h * 128] = r2d[h] * a_l[tq * 12 + h];
  }
  if (dact) {
#pragma unroll
    for (int j = 0; j < 4; ++j) {
      int e = l * 4 + j, r = e % 40, h = hj[j];
      float v = vald[j] * a_l[tq * 12 + h];
      if (r < 16) feat[(size_t)q * FEATD + h * 16 + r] = v;
      else G_l[tq * 288 + h * 24 + (r - 16)] = v;
    }
  }
  __syncthreads();
  if (t < 384) {
    int t2 = t / 96, u = t % 96, qq = q0 + t2;
    float R[9], T[3];
#pragma unroll
    for (int i = 0; i < 9; ++i) R[i] = rot[qq * 9 + i];
#pragma unroll
    for (int i = 0; i < 3; ++i) T[i] = trans[qq * 3 + i];
    const float* Gp = &G_l[(t2 * 96 + u) * 3];
    float g0 = Gp[0] - T[0], g1 = Gp[1] - T[1], g2 = Gp[2] - T[2];
    float l0 = R[0] * g0 + R[3] * g1 + R[6] * g2;  // R^T (g - t)
    float l1 = R[1] * g0 + R[4] * g1 + R[7] * g2;
    float l2 = R[2] * g0 + R[5] * g1 + R[8] * g2;
    float n2 = l0 * l0 + l1 * l1 + l2 * l2;
    float* fb = feat + (size_t)qq * FEATD;
    fb[192 + u] = l0; fb[288 + u] = l1; fb[384 + u] = l2;
    fb[480 + u] = sqrtf(fmaxf(n2, 1e-16f));
  }
}

// ----------------------------- k4: output GEMM -----------------------------
// grid (32, 12), block 256. 32x32 tile, 2x2 per thread. K = 2112 = 66*32.
__global__ __launch_bounds__(256) void k_out(
    const float* __restrict__ feat, const float* __restrict__ wout,
    const float* __restrict__ bout, float* __restrict__ out) {
  __shared__ float A[32][33];
  __shared__ float B[32][33];
  const int t = threadIdx.x;
  const int row0 = blockIdx.x * 32, col0 = blockIdx.y * 32;
  const int r0 = t >> 4, c0 = t & 15;
  float acc[2][2] = {{0.f, 0.f}, {0.f, 0.f}};
  for (int k0 = 0; k0 < FEATD; k0 += 32) {
    for (int idx = t; idx < 1024; idx += 256) {
      int i = idx >> 5, j = idx & 31;
      A[i][j] = feat[(size_t)(row0 + i) * FEATD + k0 + j];
      B[i][j] = wout[(size_t)(k0 + i) * NCHD + col0 + j];
    }
    __syncthreads();
#pragma unroll 8
    for (int kk = 0; kk < 32; ++kk) {
      float a0 = A[r0][kk], a1 = A[r0 + 16][kk];
      float b0 = B[kk][c0], b1 = B[kk][c0 + 16];
      acc[0][0] += a0 * b0; acc[0][1] += a0 * b1;
      acc[1][0] += a1 * b0; acc[1][1] += a1 * b1;
    }
    __syncthreads();
  }
#pragma unroll
  for (int r = 0; r < 2; ++r)
#pragma unroll
    for (int c = 0; c < 2; ++c) {
      int rr = row0 + r0 + r * 16, cc = col0 + c0 + c * 16;
      out[(size_t)rr * NCHD + cc] = acc[r][c] + bout[cc];
    }
}

// ------------------------------ launcher -----------------------------------
extern "C" void kernel_launch(void* const* d_in, const int* in_sizes, int n_in,
                              void* d_out, int out_size, void* d_ws, size_t ws_size,
                              hipStream_t stream) {
  const float* x1d   = (const float*)d_in[0];
  const float* x2d   = (const float*)d_in[1];
  const float* mask  = (const float*)d_in[2];
  const float* rot   = (const float*)d_in[3];
  const float* trans = (const float*)d_in[4];
  const float* raw   = (const float*)d_in[5];
  const float* wq_p  = (const float*)d_in[6];
  const float* bq_p  = (const float*)d_in[7];
  const float* wk_p  = (const float*)d_in[8];
  const float* bk_p  = (const float*)d_in[9];
  const float* wv_p  = (const float*)d_in[10];
  const float* bv_p  = (const float*)d_in[11];
  const float* wq_s  = (const float*)d_in[12];
  const float* wk_s  = (const float*)d_in[13];
  const float* wv_s  = (const float*)d_in[14];
  const float* w2d   = (const float*)d_in[15];
  const float* b2d   = (const float*)d_in[16];
  const float* wout  = (const float*)d_in[17];
  const float* bout  = (const float*)d_in[18];

  float* ws   = (float*)d_ws;
  float* qs   = ws;                  // 1024*192
  float* ks_  = qs  + 196608;
  float* vs   = ks_ + 196608;
  float* qp   = vs  + 196608;        // 1024*144
  float* kp   = qp  + 147456;
  float* vp   = kp  + 147456;        // 1024*288
  float* feat = vp  + 294912;        // 1024*2112
  float* pwf  = feat + 2162688;      // 12

  k_prep<<<dim3(1), 64, 0, stream>>>(raw, pwf);
  k_proj<<<dim3(128, 3), 256, 0, stream>>>(x1d, rot, trans, wq_p, bq_p, wk_p, bk_p,
                                           wv_p, bv_p, wq_s, wk_s, wv_s,
                                           qs, ks_, vs, qp, kp, vp);
  k_attn<<<dim3(256), 512, 0, stream>>>(x2d, mask, rot, trans, w2d, b2d, pwf,
                                        qs, ks_, vs, qp, kp, vp, feat);
  k_out<<<dim3(32, 12), 256, 0, stream>>>(feat, wout, bout, (float*)d_out);
}